// Round 10
// baseline (187.093 us; speedup 1.0000x reference)
//
#include <hip/hip_runtime.h>
#include <hip/hip_bf16.h>

typedef __bf16 bf16;
typedef __bf16 bf16x8 __attribute__((ext_vector_type(8)));
typedef float f32x4 __attribute__((ext_vector_type(4)));

static __device__ __forceinline__ f32x4 mfma16(bf16x8 a, bf16x8 b, f32x4 c) {
  return __builtin_amdgcn_mfma_f32_16x16x32_bf16(a, b, c, 0, 0, 0);
}

static __device__ __forceinline__ bf16x8 cvt8(const float* p) {
  f32x4 a0 = *(const f32x4*)p;
  f32x4 a1 = *(const f32x4*)(p + 4);
  bf16x8 r;
#pragma unroll
  for (int j = 0; j < 4; ++j) { r[j] = (bf16)a0[j]; r[4 + j] = (bf16)a1[j]; }
  return r;
}

// ---------------------------------------------------------------------------
// prep_wt: Wt[c][k] = W*(k,c). One block per c -> contiguous 512B writes.
// ---------------------------------------------------------------------------
__global__ void prep_wt(const float* __restrict__ Wq, const float* __restrict__ Wk,
                        const float* __restrict__ Wv, bf16* __restrict__ Wt) {
  int c = blockIdx.x;   // 0..319
  int k = threadIdx.x;  // 0..255
  float v;
  if (c < 32)       v = Wq[k * 32 + c];
  else if (c < 64)  v = Wk[k * 32 + (c - 32)];
  else              v = Wv[k * 256 + (c - 64)];
  Wt[c * 256 + k] = (bf16)v;
}

// ---------------------------------------------------------------------------
// qkv_gemm: grid (row-tiles, 5 col-tiles). V epilogue via LDS transpose.
// ---------------------------------------------------------------------------
__global__ __launch_bounds__(256) void qkv_gemm(
    const float* __restrict__ x, const bf16* __restrict__ Wt,
    const float* __restrict__ bq, const float* __restrict__ bk,
    const float* __restrict__ bv,
    bf16* __restrict__ Qd, bf16* __restrict__ Kd, bf16* __restrict__ Vt) {
  __shared__ __align__(16) bf16 tile[64 * 72];
  int tid = threadIdx.x;
  int lane = tid & 63, w = tid >> 6;
  int lw = lane & 15, qq = lane >> 4;
  int r0 = blockIdx.x * 64, c0 = blockIdx.y * 64;
  int bb = r0 >> 12, n0 = r0 & 4095;

  const float* arow = x + (size_t)(r0 + 16 * w + lw) * 256;
  f32x4 acc[4] = {};
#pragma unroll
  for (int kc = 0; kc < 8; ++kc) {
    bf16x8 a = cvt8(arow + kc * 32 + qq * 8);
#pragma unroll
    for (int t = 0; t < 4; ++t) {
      bf16x8 b = *(const bf16x8*)(Wt + (size_t)(c0 + 16 * t + lw) * 256 + kc * 32 + qq * 8);
      acc[t] = mfma16(a, b, acc[t]);
    }
  }
  // C/D: col = lane&15, row = (lane>>4)*4 + i
  if (c0 == 0) {
#pragma unroll
    for (int t = 0; t < 4; ++t) {
      int c = 16 * t + lw;
      float bias = (c < 32) ? bq[c] : bk[c - 32];
#pragma unroll
      for (int i = 0; i < 4; ++i) {
        int n = n0 + 16 * w + 4 * qq + i;
        bf16 hv = (bf16)(acc[t][i] + bias);
        if (c < 32) Qd[((size_t)(bb << 12) + n) * 32 + c] = hv;
        else        Kd[((size_t)(bb << 12) + n) * 32 + (c - 32)] = hv;
      }
    }
  } else {
#pragma unroll
    for (int t = 0; t < 4; ++t) {
      int cl = 16 * t + lw;
      float bias = bv[c0 - 64 + cl];
#pragma unroll
      for (int i = 0; i < 4; ++i)
        tile[cl * 72 + 16 * w + 4 * qq + i] = (bf16)(acc[t][i] + bias);
    }
    __syncthreads();
    int nl = tid & 63;
#pragma unroll
    for (int it = 0; it < 16; ++it) {
      int cl = 4 * it + w;  // wave-uniform col -> 128B contiguous stores
      Vt[((size_t)bb * 256 + (c0 - 64) + cl) * 4096 + n0 + nl] = tile[cl * 72 + nl];
    }
  }
}

// ---------------------------------------------------------------------------
// flash_attn: Br=64, 512 threads (8 waves), grid (64, batch) = 256 blocks.
// KV-SPLIT in-block: group g = w>>2 handles KV tiles [32g, 32g+32) with
// round-9's 4-wave structure (wave wr: S rows [16wr,+16), PV ch [64wr,+64),
// Pl stride 88, deferred l-sum, double-buffered P, 1 barrier/iter).
// Deferred (no-max) softmax => group partials add directly at the end.
// ---------------------------------------------------------------------------
__global__ __launch_bounds__(512, 2) void flash_attn(
    const bf16* __restrict__ Qd, const bf16* __restrict__ Kd,
    const bf16* __restrict__ Vt, const float* __restrict__ x,
    const float* __restrict__ gamma, float* __restrict__ out) {
  __shared__ __align__(16) bf16 Pl[2][2][64 * 88];   // [group][buf]
  __shared__ __align__(16) float obuf[4][1024];      // merge staging, 16 KB
  __shared__ __align__(16) float lsum2[2][64];

  int tid = threadIdx.x;
  int lane = tid & 63, w = tid >> 6;       // w = 0..7
  int lw = lane & 15, qq = lane >> 4;
  int wr = w & 3, g = w >> 2;
  int bb = blockIdx.y;
  int r0 = blockIdx.x * 64;
  int chb = 64 * wr;
  int nbase = g * 2048;                    // first kv index of this group

  const bf16* Qb = Qd + ((size_t)bb << 12) * 32;
  const bf16* Kb = Kd + ((size_t)bb << 12) * 32;
  const bf16* Vb = Vt + (size_t)bb * 256 * 4096;

  bf16x8 qf = *(const bf16x8*)(Qb + (size_t)(r0 + 16 * wr + lw) * 32 + qq * 8);

  f32x4 o[4][4] = {};          // [row-grp m][ch-tile t]
  float l_part[4] = {};
  bf16x8 kbuf0[4], kbuf1[4], vbuf0[8], vbuf1[8];

  // ---- prologue: S(first) -> Pl[g][0]; prefetch K(second), V(first) ----
#pragma unroll
  for (int t = 0; t < 4; ++t)
    kbuf0[t] = *(const bf16x8*)(Kb + (size_t)(nbase + 16 * t + lw) * 32 + qq * 8);
  {
    f32x4 s[4];
#pragma unroll
    for (int t = 0; t < 4; ++t) { f32x4 z = {}; s[t] = mfma16(qf, kbuf0[t], z); }
#pragma unroll
    for (int t = 0; t < 4; ++t)
#pragma unroll
      for (int i = 0; i < 4; ++i) {
        float p = __expf(s[t][i]);
        l_part[i] += p;
        Pl[g][0][(16 * wr + 4 * qq + i) * 88 + 16 * t + lw] = (bf16)p;
      }
  }
#pragma unroll
  for (int t = 0; t < 4; ++t)
    kbuf1[t] = *(const bf16x8*)(Kb + (size_t)(nbase + 64 + 16 * t + lw) * 32 + qq * 8);
#pragma unroll
  for (int t = 0; t < 4; ++t)
#pragma unroll
    for (int kc = 0; kc < 2; ++kc)
      vbuf0[t * 2 + kc] = *(const bf16x8*)(Vb + (size_t)(chb + 16 * t + lw) * 4096 + nbase + kc * 32 + qq * 8);
  __syncthreads();

#define FA_BODY(JL, PCUR, PNXT, KN, KC, VC, VN)                                    \
  {                                                                                \
    const int jl = (JL);                                                           \
    int n1 = nbase + (((jl + 1) & 31) * 64), n2 = nbase + (((jl + 2) & 31) * 64);  \
    bf16x8 af[4][2];                                                               \
    _Pragma("unroll") for (int m = 0; m < 4; ++m)                                  \
      _Pragma("unroll") for (int kc = 0; kc < 2; ++kc)                             \
        af[m][kc] = *(const bf16x8*)&Pl[g][PCUR][(16 * m + lw) * 88 + kc * 32 + qq * 8]; \
    if (jl < 31) {                                                                 \
      f32x4 s[4];                                                                  \
      _Pragma("unroll") for (int t = 0; t < 4; ++t) {                              \
        f32x4 z = {};                                                              \
        s[t] = mfma16(qf, KN[t], z);                                               \
      }                                                                            \
      _Pragma("unroll") for (int t = 0; t < 4; ++t)                                \
        _Pragma("unroll") for (int i = 0; i < 4; ++i) {                            \
          float p = __expf(s[t][i]);                                               \
          l_part[i] += p;                                                          \
          Pl[g][PNXT][(16 * wr + 4 * qq + i) * 88 + 16 * t + lw] = (bf16)p;        \
        }                                                                          \
      _Pragma("unroll") for (int t = 0; t < 4; ++t)                                \
        KC[t] = *(const bf16x8*)(Kb + (size_t)(n2 + 16 * t + lw) * 32 + qq * 8);   \
    }                                                                              \
    _Pragma("unroll") for (int t = 0; t < 4; ++t)                                  \
      _Pragma("unroll") for (int kc = 0; kc < 2; ++kc)                             \
        VN[t * 2 + kc] = *(const bf16x8*)(Vb + (size_t)(chb + 16 * t + lw) * 4096 + n1 + kc * 32 + qq * 8); \
    _Pragma("unroll") for (int kc = 0; kc < 2; ++kc)                               \
      _Pragma("unroll") for (int t = 0; t < 4; ++t)                                \
        _Pragma("unroll") for (int m = 0; m < 4; ++m)                              \
          o[m][t] = mfma16(af[m][kc], VC[t * 2 + kc], o[m][t]);                    \
    __syncthreads();                                                               \
  }

  for (int jj = 0; jj < 16; ++jj) {
    FA_BODY(2 * jj,     0, 1, kbuf1, kbuf0, vbuf0, vbuf1)
    FA_BODY(2 * jj + 1, 1, 0, kbuf0, kbuf1, vbuf1, vbuf0)
  }
#undef FA_BODY

  // ---- per-group l reduction (16-lane row groups) ----
#pragma unroll
  for (int i = 0; i < 4; ++i) {
    float v = l_part[i];
    v += __shfl_xor(v, 1);
    v += __shfl_xor(v, 2);
    v += __shfl_xor(v, 4);
    v += __shfl_xor(v, 8);
    if (lw == 0) lsum2[g][16 * wr + 4 * qq + i] = v;
  }

  // ---- merge group 1's o into group 0 (4 rounds, LITERAL m index) ----
#pragma unroll
  for (int mr = 0; mr < 4; ++mr) {
    __syncthreads();
    if (g == 1) {
#pragma unroll
      for (int t = 0; t < 4; ++t)
        *(f32x4*)&obuf[wr][t * 256 + lane * 4] = o[mr][t];
    }
    __syncthreads();
    if (g == 0) {
#pragma unroll
      for (int t = 0; t < 4; ++t)
        o[mr][t] += *(const f32x4*)&obuf[wr][t * 256 + lane * 4];
    }
  }
  __syncthreads();

  if (g == 0) {
    float gm = gamma[0];
#pragma unroll
    for (int m = 0; m < 4; ++m) {
      f32x4 la = *(const f32x4*)&lsum2[0][16 * m + 4 * qq];
      f32x4 lb = *(const f32x4*)&lsum2[1][16 * m + 4 * qq];
#pragma unroll
      for (int i = 0; i < 4; ++i) {
        float rinv = 1.f / (la[i] + lb[i]);
        int row = r0 + 16 * m + 4 * qq + i;
        size_t base = (((size_t)bb << 12) + row) * 256 + chb;
#pragma unroll
        for (int t = 0; t < 4; ++t)
          out[base + 16 * t + lw] = gm * (o[m][t][i] * rinv) + x[base + 16 * t + lw];
      }
    }
  }
}

extern "C" void kernel_launch(void* const* d_in, const int* in_sizes, int n_in,
                              void* d_out, int out_size, void* d_ws, size_t ws_size,
                              hipStream_t stream) {
  const float* x     = (const float*)d_in[0];
  const float* Wq    = (const float*)d_in[1];
  const float* bq    = (const float*)d_in[2];
  const float* Wk    = (const float*)d_in[3];
  const float* bk    = (const float*)d_in[4];
  const float* Wv    = (const float*)d_in[5];
  const float* bv    = (const float*)d_in[6];
  const float* gamma = (const float*)d_in[7];
  float* out = (float*)d_out;

  const size_t WT_E = 320 * 256;
  const size_t QK_E = (size_t)4096 * 32;
  const size_t VT_E = (size_t)256 * 4096;
  size_t full_bytes = (WT_E + 4 * 2 * QK_E + 4 * VT_E) * sizeof(bf16);

  bf16* Wt = (bf16*)d_ws;
  prep_wt<<<dim3(320), dim3(256), 0, stream>>>(Wq, Wk, Wv, Wt);

  if (ws_size >= full_bytes) {
    bf16* Qd = Wt + WT_E;
    bf16* Kd = Qd + 4 * QK_E;
    bf16* Vt = Kd + 4 * QK_E;
    qkv_gemm<<<dim3(256, 5), dim3(256), 0, stream>>>(x, Wt, bq, bk, bv, Qd, Kd, Vt);
    flash_attn<<<dim3(64, 4), dim3(512), 0, stream>>>(Qd, Kd, Vt, x, gamma, out);
  } else {
    bf16* Qd = Wt + WT_E;
    bf16* Kd = Qd + QK_E;
    bf16* Vt = Kd + QK_E;
    for (int b = 0; b < 4; ++b) {
      const float* xb = x + (size_t)b * 4096 * 256;
      float* outb = out + (size_t)b * 4096 * 256;
      qkv_gemm<<<dim3(64, 5), dim3(256), 0, stream>>>(xb, Wt, bq, bk, bv, Qd, Kd, Vt);
      flash_attn<<<dim3(64, 1), dim3(512), 0, stream>>>(Qd, Kd, Vt, xb, gamma, outb);
    }
  }
}